// Round 1
// baseline (272.767 us; speedup 1.0000x reference)
//
#include <hip/hip_runtime.h>
#include <hip/hip_bf16.h>

// Forward warp (bilinear splatting):
//   img  [B=8, C=3, H=180, W=320] f32
//   flow [B=8, 2,  H=180, W=320] f32
//   scale (int, =4) -> out [B, C, H*scale, W*scale] f32
// mapping = (coords + flow) * scale ; scatter-add 4 bilinear corners.

#define B_ 8
#define C_ 3
#define H_ 180
#define W_ 320

__global__ void splat_kernel(const float* __restrict__ img,
                             const float* __restrict__ flow,
                             const int* __restrict__ scale_p,
                             float* __restrict__ out) {
    const int n = B_ * H_ * W_;
    int idx = blockIdx.x * blockDim.x + threadIdx.x;
    if (idx >= n) return;

    const int s = *scale_p;          // uniform load -> scalar cached
    const int Ho = H_ * s;
    const int Wo = W_ * s;

    int w = idx % W_;
    int t = idx / W_;
    int h = t % H_;
    int b = t / H_;

    // flow: [B,2,H,W]
    const int hw = h * W_ + w;
    float fx = flow[((b * 2 + 0) * H_) * W_ + hw];
    float fy = flow[((b * 2 + 1) * H_) * W_ + hw];

    float x = ((float)w + fx) * (float)s;
    float y = ((float)h + fy) * (float)s;

    float x0f = floorf(x);
    float y0f = floorf(y);
    float ax = x - x0f;   // in [0,1)
    float ay = y - y0f;
    int ix0 = (int)x0f;
    int iy0 = (int)y0f;

    // img: [B,C,H,W]
    const size_t img_b = (size_t)b * C_ * H_ * W_;
    float v0 = img[img_b + 0 * (size_t)(H_ * W_) + hw];
    float v1 = img[img_b + 1 * (size_t)(H_ * W_) + hw];
    float v2 = img[img_b + 2 * (size_t)(H_ * W_) + hw];

    const size_t out_b   = (size_t)b * C_ * Ho * Wo;
    const size_t out_chs = (size_t)Ho * Wo;

    float wx[2] = {1.0f - ax, ax};
    float wy[2] = {1.0f - ay, ay};

    #pragma unroll
    for (int ky = 0; ky < 2; ++ky) {
        int yi = iy0 + ky;
        if (yi < 0 || yi > Ho - 1) continue;
        #pragma unroll
        for (int kx = 0; kx < 2; ++kx) {
            int xi = ix0 + kx;
            if (xi < 0 || xi > Wo - 1) continue;
            float wt = wx[kx] * wy[ky];
            size_t base = out_b + (size_t)yi * Wo + (size_t)xi;
            atomicAdd(&out[base + 0 * out_chs], v0 * wt);
            atomicAdd(&out[base + 1 * out_chs], v1 * wt);
            atomicAdd(&out[base + 2 * out_chs], v2 * wt);
        }
    }
}

extern "C" void kernel_launch(void* const* d_in, const int* in_sizes, int n_in,
                              void* d_out, int out_size, void* d_ws, size_t ws_size,
                              hipStream_t stream) {
    const float* img   = (const float*)d_in[0];
    const float* flow  = (const float*)d_in[1];
    const int*   scale = (const int*)d_in[2];
    float* out = (float*)d_out;

    // Output must be zeroed every call (harness does not re-poison between replays).
    hipMemsetAsync(out, 0, (size_t)out_size * sizeof(float), stream);

    const int n = B_ * H_ * W_;
    const int block = 256;
    const int grid = (n + block - 1) / block;
    splat_kernel<<<grid, block, 0, stream>>>(img, flow, scale, out);
}

// Round 2
// 87.424 us; speedup vs baseline: 3.1200x; 3.1200x over previous
//
#include <hip/hip_runtime.h>
#include <hip/hip_bf16.h>

// Forward warp (bilinear splatting), binning + LDS-tile accumulation.
//   img  [B=8, C=3, H=180, W=320] f32
//   flow [B=8, 2,  H=180, W=320] f32
//   scale=4 -> out [B, C, 720, 1280] f32

#define B_ 8
#define C_ 3
#define H_ 180
#define W_ 320
#define HW_ (H_ * W_)
#define SCALE_ 4
#define Ho_ (H_ * SCALE_)          // 720
#define Wo_ (W_ * SCALE_)          // 1280
#define TH_ 40
#define TW_ 64
#define NTY_ (Ho_ / TH_)           // 18
#define NTX_ (Wo_ / TW_)           // 20
#define NTILES_ (B_ * NTY_ * NTX_) // 2880
#define NPIX_ (B_ * H_ * W_)       // 460800 (= 1800 * 256 exactly)
#define TILE_ELEMS_ (C_ * TH_ * TW_) // 7680 floats = 30 KB

// ---------- mapping helper: returns true if pixel has any valid corner ----------
__device__ __forceinline__ bool pixel_bin(const float* __restrict__ flow,
                                          int idx, int& b, int& bin) {
    int w = idx % W_;
    int t = idx / W_;
    int h = t % H_;
    b = t / H_;
    int hw = h * W_ + w;
    float fx = flow[(b * 2 + 0) * HW_ + hw];
    float fy = flow[(b * 2 + 1) * HW_ + hw];
    float x = ((float)w + fx) * (float)SCALE_;
    float y = ((float)h + fy) * (float)SCALE_;
    int ix0 = (int)floorf(x);
    int iy0 = (int)floorf(y);
    int xlo = max(ix0, 0), xhi = min(ix0 + 1, Wo_ - 1);
    int ylo = max(iy0, 0), yhi = min(iy0 + 1, Ho_ - 1);
    if (xlo > xhi || ylo > yhi) return false;
    int tx = xlo / TW_;
    int ty = ylo / TH_;
    bin = (b * NTY_ + ty) * NTX_ + tx;
    return true;
}

// ---------- pass A: per-bin counts (wave-aggregated atomics) ----------
__global__ __launch_bounds__(256) void count_kernel(const float* __restrict__ flow,
                                                    unsigned* __restrict__ counts) {
    int idx = blockIdx.x * blockDim.x + threadIdx.x;   // grid exactly NPIX_
    int b, bin = -1;
    bool valid = pixel_bin(flow, idx, b, bin);
    unsigned long long todo = __ballot(valid);
    int lane = threadIdx.x & 63;
    while (todo) {
        int leader = __ffsll((long long)todo) - 1;
        int key = __shfl(bin, leader);
        unsigned long long members = __ballot(valid && bin == key);
        if (valid && bin == key) {
            unsigned long long lower = members & ((1ull << lane) - 1ull);
            if (__popcll(lower) == 0)
                atomicAdd(&counts[key], (unsigned)__popcll(members));
        }
        todo &= ~members;
    }
}

// ---------- pass B: exclusive scan of counts -> offs, cursor ----------
#define SCAN_PER_T 12   // 256*12 = 3072 >= 2880
__global__ __launch_bounds__(256) void scan_kernel(const unsigned* __restrict__ counts,
                                                   unsigned* __restrict__ offs,
                                                   unsigned* __restrict__ cursor) {
    __shared__ unsigned part[256];
    int tid = threadIdx.x;
    unsigned local[SCAN_PER_T];
    unsigned sum = 0;
    for (int i = 0; i < SCAN_PER_T; ++i) {
        int j = tid * SCAN_PER_T + i;
        unsigned c = (j < NTILES_) ? counts[j] : 0u;
        local[i] = sum;
        sum += c;
    }
    part[tid] = sum;
    __syncthreads();
    for (int off = 1; off < 256; off <<= 1) {
        unsigned v = (tid >= off) ? part[tid - off] : 0u;
        __syncthreads();
        part[tid] += v;
        __syncthreads();
    }
    unsigned base = (tid > 0) ? part[tid - 1] : 0u;
    for (int i = 0; i < SCAN_PER_T; ++i) {
        int j = tid * SCAN_PER_T + i;
        if (j < NTILES_) {
            unsigned o = base + local[i];
            offs[j] = o;
            cursor[j] = o;
        }
    }
}

// ---------- pass C: scatter pixel indices into bins (wave-aggregated slots) ----------
__global__ __launch_bounds__(256) void fill_kernel(const float* __restrict__ flow,
                                                   unsigned* __restrict__ cursor,
                                                   unsigned* __restrict__ records) {
    int idx = blockIdx.x * blockDim.x + threadIdx.x;
    int b, bin = -1;
    bool valid = pixel_bin(flow, idx, b, bin);
    unsigned long long todo = __ballot(valid);
    int lane = threadIdx.x & 63;
    while (todo) {
        int leader = __ffsll((long long)todo) - 1;
        int key = __shfl(bin, leader);
        unsigned long long members = __ballot(valid && bin == key);
        if (valid && bin == key) {
            unsigned long long lower = members & ((1ull << lane) - 1ull);
            int rank = __popcll(lower);
            unsigned grpbase = 0;
            if (rank == 0)
                grpbase = atomicAdd(&cursor[key], (unsigned)__popcll(members));
            grpbase = __shfl(grpbase, leader);
            records[grpbase + rank] = (unsigned)idx;
        }
        todo &= ~members;
    }
}

// ---------- pass D: per-tile LDS accumulate + coalesced exclusive write ----------
__global__ __launch_bounds__(256) void accum_kernel(const float* __restrict__ img,
                                                    const float* __restrict__ flow,
                                                    const unsigned* __restrict__ counts,
                                                    const unsigned* __restrict__ offs,
                                                    const unsigned* __restrict__ records,
                                                    float* __restrict__ out) {
    __shared__ __align__(16) float acc[TILE_ELEMS_];
    int tile = blockIdx.x;
    int tx = tile % NTX_;
    int tt = tile / NTX_;
    int ty = tt % NTY_;
    int b  = tt / NTY_;
    int px0 = tx * TW_;
    int py0 = ty * TH_;

    for (int i = threadIdx.x; i < TILE_ELEMS_; i += 256) acc[i] = 0.0f;
    __syncthreads();

    const float* flowx = flow + (size_t)(b * 2 + 0) * HW_;
    const float* flowy = flow + (size_t)(b * 2 + 1) * HW_;
    const float* imgb  = img + (size_t)b * C_ * HW_;

    // A record binned at (tx,ty) can only put corners in tiles (tx..tx+1, ty..ty+1),
    // so this tile scans bins (tx-1..tx, ty-1..ty).
    for (int dty = -1; dty <= 0; ++dty) {
        int nty = ty + dty;
        if (nty < 0) continue;
        for (int dtx = -1; dtx <= 0; ++dtx) {
            int ntx = tx + dtx;
            if (ntx < 0) continue;
            int bin = (b * NTY_ + nty) * NTX_ + ntx;
            unsigned start = offs[bin];
            unsigned cnt   = counts[bin];
            for (unsigned r = start + threadIdx.x; r < start + cnt; r += 256) {
                unsigned pidx = records[r];
                int w = pidx % W_;
                int t2 = pidx / W_;
                int h = t2 % H_;
                int hw = h * W_ + w;
                float fx = flowx[hw];
                float fy = flowy[hw];
                float x = ((float)w + fx) * (float)SCALE_;
                float y = ((float)h + fy) * (float)SCALE_;
                float x0f = floorf(x), y0f = floorf(y);
                int ix0 = (int)x0f, iy0 = (int)y0f;
                // reject if footprint misses this tile
                if (ix0 + 1 < px0 || ix0 > px0 + TW_ - 1 ||
                    iy0 + 1 < py0 || iy0 > py0 + TH_ - 1) continue;
                float ax = x - x0f, ay = y - y0f;
                float v0 = imgb[0 * HW_ + hw];
                float v1 = imgb[1 * HW_ + hw];
                float v2 = imgb[2 * HW_ + hw];
                float wx[2] = {1.0f - ax, ax};
                float wy[2] = {1.0f - ay, ay};
                #pragma unroll
                for (int ky = 0; ky < 2; ++ky) {
                    int yi = iy0 + ky;
                    if (yi < py0 || yi >= py0 + TH_) continue;   // in-tile => in-image
                    #pragma unroll
                    for (int kx = 0; kx < 2; ++kx) {
                        int xi = ix0 + kx;
                        if (xi < px0 || xi >= px0 + TW_) continue;
                        float wt = wx[kx] * wy[ky];
                        int la = (yi - py0) * TW_ + (xi - px0);
                        atomicAdd(&acc[0 * TH_ * TW_ + la], v0 * wt);
                        atomicAdd(&acc[1 * TH_ * TW_ + la], v1 * wt);
                        atomicAdd(&acc[2 * TH_ * TW_ + la], v2 * wt);
                    }
                }
            }
        }
    }
    __syncthreads();

    // exclusive coalesced write-out, float4
    const size_t outb = (size_t)b * C_ * Ho_ * Wo_;
    for (int j = threadIdx.x; j < TILE_ELEMS_ / 4; j += 256) {
        int f = j * 4;
        int c = f / (TH_ * TW_);
        int rem = f - c * (TH_ * TW_);
        int yy = rem / TW_;
        int xx = rem - yy * TW_;
        float4 v = *reinterpret_cast<const float4*>(&acc[f]);
        *reinterpret_cast<float4*>(
            &out[outb + (size_t)c * Ho_ * Wo_ + (size_t)(py0 + yy) * Wo_ + (px0 + xx)]) = v;
    }
}

// ---------- fallback: naive global-atomic splat (used if ws too small / scale != 4) ----------
__global__ __launch_bounds__(256) void splat_naive(const float* __restrict__ img,
                                                   const float* __restrict__ flow,
                                                   const int* __restrict__ scale_p,
                                                   float* __restrict__ out) {
    int idx = blockIdx.x * blockDim.x + threadIdx.x;
    if (idx >= NPIX_) return;
    const int s = *scale_p;
    const int Ho = H_ * s, Wo = W_ * s;
    int w = idx % W_;
    int t = idx / W_;
    int h = t % H_;
    int b = t / H_;
    const int hw = h * W_ + w;
    float fx = flow[((b * 2 + 0) * H_) * W_ + hw];
    float fy = flow[((b * 2 + 1) * H_) * W_ + hw];
    float x = ((float)w + fx) * (float)s;
    float y = ((float)h + fy) * (float)s;
    float x0f = floorf(x), y0f = floorf(y);
    float ax = x - x0f, ay = y - y0f;
    int ix0 = (int)x0f, iy0 = (int)y0f;
    const size_t img_b = (size_t)b * C_ * HW_;
    float v0 = img[img_b + 0 * (size_t)HW_ + hw];
    float v1 = img[img_b + 1 * (size_t)HW_ + hw];
    float v2 = img[img_b + 2 * (size_t)HW_ + hw];
    const size_t out_b = (size_t)b * C_ * Ho * Wo;
    const size_t out_chs = (size_t)Ho * Wo;
    float wx[2] = {1.0f - ax, ax};
    float wy[2] = {1.0f - ay, ay};
    #pragma unroll
    for (int ky = 0; ky < 2; ++ky) {
        int yi = iy0 + ky;
        if (yi < 0 || yi > Ho - 1) continue;
        #pragma unroll
        for (int kx = 0; kx < 2; ++kx) {
            int xi = ix0 + kx;
            if (xi < 0 || xi > Wo - 1) continue;
            float wt = wx[kx] * wy[ky];
            size_t base = out_b + (size_t)yi * Wo + (size_t)xi;
            atomicAdd(&out[base + 0 * out_chs], v0 * wt);
            atomicAdd(&out[base + 1 * out_chs], v1 * wt);
            atomicAdd(&out[base + 2 * out_chs], v2 * wt);
        }
    }
}

extern "C" void kernel_launch(void* const* d_in, const int* in_sizes, int n_in,
                              void* d_out, int out_size, void* d_ws, size_t ws_size,
                              hipStream_t stream) {
    const float* img   = (const float*)d_in[0];
    const float* flow  = (const float*)d_in[1];
    const int*   scale = (const int*)d_in[2];
    float* out = (float*)d_out;

    // ws layout: counts[NTILES] | offs[NTILES] | cursor[NTILES] | records[NPIX]
    const size_t tbl = (size_t)NTILES_ * sizeof(unsigned);
    const size_t need = 3 * tbl + (size_t)NPIX_ * sizeof(unsigned);
    const bool scale4 = (out_size == B_ * C_ * Ho_ * Wo_);

    if (scale4 && ws_size >= need) {
        unsigned* counts  = (unsigned*)d_ws;
        unsigned* offs    = counts + NTILES_;
        unsigned* cursor  = offs + NTILES_;
        unsigned* records = cursor + NTILES_;

        hipMemsetAsync(counts, 0, tbl, stream);
        count_kernel<<<NPIX_ / 256, 256, 0, stream>>>(flow, counts);
        scan_kernel<<<1, 256, 0, stream>>>(counts, offs, cursor);
        fill_kernel<<<NPIX_ / 256, 256, 0, stream>>>(flow, cursor, records);
        accum_kernel<<<NTILES_, 256, 0, stream>>>(img, flow, counts, offs, records, out);
    } else {
        hipMemsetAsync(out, 0, (size_t)out_size * sizeof(float), stream);
        splat_naive<<<(NPIX_ + 255) / 256, 256, 0, stream>>>(img, flow, scale, out);
    }
}